// Round 6
// baseline (46.039 us; speedup 1.0000x reference)
//
#include <hip/hip_runtime.h>

#define Bn 1024
#define Pn 128
#define Fn 512
#define Dn 256
#define THETA 1e-7f
#define BP (Bn * Pn)
#define SB 8            // F-split of reduction kernel
#define FCB (Fn / SB)   // 64

// ---------------------------------------------------------------------------
// GEMM: C = [x; prototypes] @ fb^T.  1-wave blocks, 32x32 tile, 4x4/thread.
// Per wave-k-iter: 2 ds_read_b128 (~24 LDS cyc) vs 16 v_fma (32 VALU cyc)
// -> VALU-bound at 1 wave/CU (vs round-1's 3x LDS-oversubscription).
// Grid (Fn/32, (Bn+Pn)/32) = 16 x 36 = 576 blocks.
// xf rows < Bn -> xf[r][c]; rows >= Bn -> pfT[c][p] (transposed store).
// ---------------------------------------------------------------------------
__global__ __launch_bounds__(64)
void gemm_feat(const float* __restrict__ x, const float* __restrict__ prot,
               const float* __restrict__ fb, float* __restrict__ xf,
               float* __restrict__ pfT)
{
    __shared__ float As[32][36];   // [k][r], 36-f32 row pitch (16B-aligned)
    __shared__ float Fs[32][36];   // [k][c]
    const int tid = threadIdx.x;   // 0..63
    const int cb  = blockIdx.x * 32;
    const int rb  = blockIdx.y * 32;
    const int tx  = tid & 7;       // 8 col-groups of 4
    const int ty  = tid >> 3;      // 8 row-groups of 4

    float acc[4][4] = {};

    for (int k0 = 0; k0 < Dn; k0 += 32) {
        #pragma unroll
        for (int q = 0; q < 4; ++q) {
            const int g  = tid * 4 + q;   // 0..255
            const int r  = g >> 3;        // 0..31
            const int k4 = g & 7;         // float4 slot within 32-k chunk
            const int rr = rb + r;
            const float* asrc = (rr < Bn) ? (x + (size_t)rr * Dn)
                                          : (prot + (size_t)(rr - Bn) * Dn);
            const float4 av = *(const float4*)(asrc + k0 + k4 * 4);
            const float4 fv = *(const float4*)(fb + (size_t)(cb + r) * Dn + k0 + k4 * 4);
            As[k4*4+0][r] = av.x; As[k4*4+1][r] = av.y;
            As[k4*4+2][r] = av.z; As[k4*4+3][r] = av.w;
            Fs[k4*4+0][r] = fv.x; Fs[k4*4+1][r] = fv.y;
            Fs[k4*4+2][r] = fv.z; Fs[k4*4+3][r] = fv.w;
        }
        __syncthreads();
        #pragma unroll 8
        for (int k = 0; k < 32; ++k) {
            const float4 a = *(const float4*)&As[k][ty * 4];
            const float4 f = *(const float4*)&Fs[k][tx * 4];
            const float aa[4] = {a.x, a.y, a.z, a.w};
            const float ff[4] = {f.x, f.y, f.z, f.w};
            #pragma unroll
            for (int i = 0; i < 4; ++i)
                #pragma unroll
                for (int j = 0; j < 4; ++j)
                    acc[i][j] = fmaf(aa[i], ff[j], acc[i][j]);
        }
        __syncthreads();
    }

    #pragma unroll
    for (int i = 0; i < 4; ++i) {
        const int r = rb + ty * 4 + i;
        if (r < Bn) {
            float4 v = make_float4(acc[i][0], acc[i][1], acc[i][2], acc[i][3]);
            *(float4*)(xf + (size_t)r * Fn + cb + tx * 4) = v;
        } else {
            #pragma unroll
            for (int j = 0; j < 4; ++j)
                pfT[(size_t)(cb + tx * 4 + j) * Pn + (r - Bn)] = acc[i][j];
        }
    }
}

// ---------------------------------------------------------------------------
// Tversky reduction over one F-chunk (round-1 exact math).
//   inter = sum rx*rp ; M = sum min(rx,rp) ; SXB = sum rx*bp ; SPB = sum rp*bx
//   partW = alpha*(SXB - M) + beta*(SPB - M)
// Thread = 2b x 4p. Block tile 64b x 32p. Grid (16, 4, SB) = 512 blocks.
// ---------------------------------------------------------------------------
__global__ __launch_bounds__(256)
void tversky_main(const float* __restrict__ xf, const float* __restrict__ pfT,
                  const float* __restrict__ alpha_p, const float* __restrict__ beta_p,
                  float* __restrict__ partI, float* __restrict__ partW)
{
    const int tid = threadIdx.x;
    const int tx  = tid & 7;
    const int ty  = tid >> 3;
    const int p0  = blockIdx.y * 32 + tx * 4;
    const int b0  = blockIdx.x * 64 + ty * 2;
    const int s   = blockIdx.z;
    const int f0  = s * FCB;

    float aI[2][4] = {};
    float aM[2][4] = {};
    float aX[2][4] = {};
    float aP[2][4] = {};

    #pragma unroll 4
    for (int f = f0; f < f0 + FCB; f += 4) {
        float4 pr[4];
        #pragma unroll
        for (int j = 0; j < 4; ++j)
            pr[j] = *(const float4*)(pfT + (size_t)(f + j) * Pn + p0);
        float4 xr[2];
        #pragma unroll
        for (int i = 0; i < 2; ++i)
            xr[i] = *(const float4*)(xf + (size_t)(b0 + i) * Fn + f);

        #pragma unroll
        for (int j = 0; j < 4; ++j) {
            const float pv[4] = {pr[j].x, pr[j].y, pr[j].z, pr[j].w};
            float rp[4], bp[4];
            #pragma unroll
            for (int q = 0; q < 4; ++q) {
                rp[q] = fmaxf(pv[q], 0.f);
                bp[q] = (pv[q] > 0.f) ? 1.f : 0.f;
            }
            #pragma unroll
            for (int i = 0; i < 2; ++i) {
                const float* xcomp = (const float*)&xr[i];
                const float xv = xcomp[j];
                const float rx = fmaxf(xv, 0.f);
                const float bx = (xv > 0.f) ? 1.f : 0.f;
                #pragma unroll
                for (int q = 0; q < 4; ++q) {
                    aI[i][q]  = fmaf(rx, rp[q], aI[i][q]);
                    aM[i][q] += fminf(rx, rp[q]);
                    aX[i][q]  = fmaf(rx, bp[q], aX[i][q]);
                    aP[i][q]  = fmaf(rp[q], bx, aP[i][q]);
                }
            }
        }
    }

    const float alpha = *alpha_p;
    const float beta  = *beta_p;
    #pragma unroll
    for (int i = 0; i < 2; ++i) {
        #pragma unroll
        for (int q = 0; q < 4; ++q) {
            const size_t idx = (size_t)s * BP + (size_t)(b0 + i) * Pn + (p0 + q);
            partI[idx] = aI[i][q];
            partW[idx] = alpha * (aX[i][q] - aM[i][q])
                       + beta  * (aP[i][q] - aM[i][q]);
        }
    }
}

// ---------------------------------------------------------------------------
// Epilogue: reduce SB partials, compute ratio.
// ---------------------------------------------------------------------------
__global__ __launch_bounds__(256)
void tversky_epi(const float* __restrict__ partI, const float* __restrict__ partW,
                 float* __restrict__ out)
{
    const int idx = blockIdx.x * 256 + threadIdx.x;
    float I = 0.f, W = 0.f;
    #pragma unroll
    for (int s = 0; s < SB; ++s) {
        I += partI[(size_t)s * BP + idx];
        W += partW[(size_t)s * BP + idx];
    }
    out[idx] = I / (I + W + THETA);
}

extern "C" void kernel_launch(void* const* d_in, const int* in_sizes, int n_in,
                              void* d_out, int out_size, void* d_ws, size_t ws_size,
                              hipStream_t stream)
{
    const float* x     = (const float*)d_in[0];
    const float* prot  = (const float*)d_in[1];
    const float* fb    = (const float*)d_in[2];
    const float* alpha = (const float*)d_in[3];
    const float* beta  = (const float*)d_in[4];
    float* out = (float*)d_out;

    float* xf    = (float*)d_ws;                 // Bn*Fn
    float* pfT   = xf + (size_t)Bn * Fn;         // Fn*Pn
    float* partI = pfT + (size_t)Fn * Pn;        // SB*BP
    float* partW = partI + (size_t)SB * BP;      // SB*BP

    dim3 gg(Fn / 32, (Bn + Pn) / 32);            // 16 x 36 = 576 blocks, 64 thr
    gemm_feat<<<gg, 64, 0, stream>>>(x, prot, fb, xf, pfT);

    dim3 gm(Bn / 64, Pn / 32, SB);               // 16 x 4 x 8 = 512 blocks
    tversky_main<<<gm, 256, 0, stream>>>(xf, pfT, alpha, beta, partI, partW);

    tversky_epi<<<BP / 256, 256, 0, stream>>>(partI, partW, out);
}